// Round 7
// baseline (212.577 us; speedup 1.0000x reference)
//
#include <hip/hip_runtime.h>
#include <hip/hip_bf16.h>
#include <stdint.h>

#define DOUT 1024
#define NMAX 16384

typedef __attribute__((ext_vector_type(8))) short short8;
typedef __attribute__((ext_vector_type(4))) float floatx4;

__device__ __forceinline__ unsigned short f2bf(float f) {
  union { float f; uint32_t u; } v;
  v.f = f;
  return (unsigned short)((v.u + 0x7FFFu + ((v.u >> 16) & 1u)) >> 16);  // RNE
}

// pack 8 fp32 -> 8 bf16 (RNE)
__device__ __forceinline__ short8 cvt8(float4 a, float4 b) {
  __hip_bfloat162 p0 = __float22bfloat162_rn(make_float2(a.x, a.y));
  __hip_bfloat162 p1 = __float22bfloat162_rn(make_float2(a.z, a.w));
  __hip_bfloat162 p2 = __float22bfloat162_rn(make_float2(b.x, b.y));
  __hip_bfloat162 p3 = __float22bfloat162_rn(make_float2(b.z, b.w));
  union { __hip_bfloat162 h[4]; short8 s; } u;
  u.h[0] = p0; u.h[1] = p1; u.h[2] = p2; u.h[3] = p3;
  return u.s;
}

// ---------------------------------------------------------------------------
// Fragment-swizzled layout (both A and B operands of mfma_f32_16x16x32_bf16):
//   unit (tile16 t, kchunk32 c, lane l) stores M[t*16 + (l&15)][c*32 + (l>>4)*8 .. +8]
//   at elem offset ((t*C + c)*64 + l)*8,  C = H/32.
// A fragment load in the GEMM = one coalesced global_load_dwordx4 per lane.
// ---------------------------------------------------------------------------
template <int H>
__device__ __forceinline__ void cvtB_swz(const float* __restrict__ w,
                                         unsigned short* __restrict__ dst, int u) {
  constexpr int C = H / 32;
  int l = u & 63;
  int rest = u >> 6;
  int c = rest & (C - 1);
  int nt = rest / C;
  const float* s = w + (size_t)(nt * 16 + (l & 15)) * H + c * 32 + ((l >> 4) << 3);
  float4 v0 = *(const float4*)s;
  float4 v1 = *(const float4*)(s + 4);
  *(short8*)(dst + (((size_t)nt * C + c) * 64 + l) * 8) = cvt8(v0, v1);
}

// classify tokens (blocks 0..63) + build swizzled bf16 B (blocks 64..735)
__global__ __launch_bounds__(256) void classify_cvt_kernel(
    const int* __restrict__ idx, int* __restrict__ cnt,
    int* __restrict__ bucket, int* __restrict__ blocal, int N,
    const float* __restrict__ w0, const float* __restrict__ w1,
    const float* __restrict__ w2, unsigned short* __restrict__ wb0,
    unsigned short* __restrict__ wb1, unsigned short* __restrict__ wb2) {
  if (blockIdx.x < 64) {
    int n = blockIdx.x * 256 + threadIdx.x;
    int lane = threadIdx.x & 63;
    int c = -1, v = 0;
    if (n < N) {
      v = idx[n];
      c = (v < 20000) ? 0 : ((v < 40000) ? 1 : 2);
    }
#pragma unroll
    for (int k = 0; k < 3; ++k) {
      unsigned long long m = __ballot(c == k);
      if (c == k) {
        int leader = __ffsll((unsigned long long)m) - 1;
        int base = 0;
        if (lane == leader) base = atomicAdd(&cnt[k], (int)__popcll(m));
        base = __shfl(base, leader);
        int rank = (int)__popcll(m & ((1ull << (unsigned)lane) - 1ull));
        int lo = (k == 0) ? 0 : (k == 1) ? 20000 : 40000;
        bucket[k * NMAX + base + rank] = n;
        blocal[k * NMAX + base + rank] = v - lo;
      }
    }
  } else {
    // B swizzle units: z0 64*32*64=131072, z1 64*8*64=32768, z2 64*2*64=8192
    int i = (blockIdx.x - 64) * 256 + threadIdx.x;
    if (i < 131072) cvtB_swz<1024>(w0, wb0, i);
    else if (i < 163840) cvtB_swz<256>(w1, wb1, i - 131072);
    else if (i < 172032) cvtB_swz<64>(w2, wb2, i - 163840);
  }
}

// gather used emb rows -> compacted, fragment-swizzled bf16 A per cluster
__global__ __launch_bounds__(256) void gather_swz(
    const float* __restrict__ emb0, const float* __restrict__ emb1,
    const float* __restrict__ emb2, const int* __restrict__ blocal,
    const int* __restrict__ cnt, unsigned short* __restrict__ a0,
    unsigned short* __restrict__ a1, unsigned short* __restrict__ a2) {
  const int z = blockIdx.z;
  const int H = (z == 0) ? 1024 : (z == 1) ? 256 : 64;
  const int lc = (z == 0) ? 5 : (z == 1) ? 3 : 1;  // log2(H/32)
  const int C = 1 << lc;
  const float* emb = (z == 0) ? emb0 : (z == 1) ? emb1 : emb2;
  unsigned short* asw = (z == 0) ? a0 : (z == 1) ? a1 : a2;
  const int* bl = blocal + z * NMAX;
  const int count = cnt[z];
  const int mtiles = (count + 15) >> 4;
  const int total = (mtiles << lc) << 6;
  for (int i = blockIdx.x * 256 + threadIdx.x; i < total; i += gridDim.x * 256) {
    int l = i & 63;
    int rest = i >> 6;
    int c = rest & (C - 1);
    int mt = rest >> lc;
    int m = (mt << 4) + (l & 15);
    int loc = (m < count) ? bl[m] : 0;
    const float* s = emb + (size_t)loc * H + (c << 5) + ((l >> 4) << 3);
    float4 v0 = *(const float4*)s;
    float4 v1 = *(const float4*)(s + 4);
    *(short8*)(asw + (((size_t)(mt << lc) + c) * 64 + l) * 8) = cvt8(v0, v1);
  }
}

// ---------------------------------------------------------------------------
// Barrier-free, LDS-free MFMA GEMM. Block = 128x128 (4 waves, each 64x64 as
// 4x4 16x16x32 tiles). All fragments loaded as coalesced dwordx4 from the
// swizzled A/B buffers; next-iter fragments prefetched in registers — no
// __syncthreads => no vmcnt(0) drain, loads stay in flight across MFMAs.
// ---------------------------------------------------------------------------
template <int H>
__device__ __forceinline__ void gemm_body(
    const unsigned short* __restrict__ Asw, const unsigned short* __restrict__ Bsw,
    int count, const int* __restrict__ bucket, float* __restrict__ out) {
  constexpr int C = H / 32;
  const int m0 = blockIdx.y * 128;
  if (m0 >= count) return;
  const int n0 = blockIdx.x * 128;

  const int tid = threadIdx.x;
  const int wave = tid >> 6;
  const int lane = tid & 63;
  const int quad = lane >> 4;
  const int l16 = lane & 15;
  const int wm = wave & 1;   // m-half (64 rows)
  const int wn = wave >> 1;  // n-half (64 cols)

  // fragment base pointers: frag(f, c) at base + (f*C + c)*512 elems
  const unsigned short* abase =
      Asw + (((size_t)(m0 / 16 + wm * 4) * C) * 64 + lane) * 8;
  const unsigned short* bbase =
      Bsw + (((size_t)(n0 / 16 + wn * 4) * C) * 64 + lane) * 8;

  floatx4 acc[4][4];
#pragma unroll
  for (int i = 0; i < 4; ++i)
#pragma unroll
    for (int j = 0; j < 4; ++j) acc[i][j] = (floatx4){0.f, 0.f, 0.f, 0.f};

  short8 curA[4], curB[4], nxtA[4], nxtB[4];
#pragma unroll
  for (int f = 0; f < 4; ++f) {
    curA[f] = *(const short8*)(abase + (size_t)f * C * 512);
    curB[f] = *(const short8*)(bbase + (size_t)f * C * 512);
  }

#pragma unroll 2
  for (int c = 0; c < C - 1; ++c) {
#pragma unroll
    for (int f = 0; f < 4; ++f) {
      nxtA[f] = *(const short8*)(abase + ((size_t)f * C + c + 1) * 512);
      nxtB[f] = *(const short8*)(bbase + ((size_t)f * C + c + 1) * 512);
    }
#pragma unroll
    for (int mi = 0; mi < 4; ++mi)
#pragma unroll
      for (int ni = 0; ni < 4; ++ni)
        acc[mi][ni] = __builtin_amdgcn_mfma_f32_16x16x32_bf16(
            curA[mi], curB[ni], acc[mi][ni], 0, 0, 0);
#pragma unroll
    for (int f = 0; f < 4; ++f) { curA[f] = nxtA[f]; curB[f] = nxtB[f]; }
  }
#pragma unroll
  for (int mi = 0; mi < 4; ++mi)
#pragma unroll
    for (int ni = 0; ni < 4; ++ni)
      acc[mi][ni] = __builtin_amdgcn_mfma_f32_16x16x32_bf16(
          curA[mi], curB[ni], acc[mi][ni], 0, 0, 0);

  // epilogue: scatter rows to out[tok][*]  (C/D: col=lane&15, row=quad*4+reg)
  const int colBase = n0 + wn * 64 + l16;
#pragma unroll
  for (int mi = 0; mi < 4; ++mi) {
#pragma unroll
    for (int r = 0; r < 4; ++r) {
      int m = m0 + wm * 64 + mi * 16 + quad * 4 + r;
      int tok = (m < count) ? bucket[m] : -1;
      if (tok >= 0) {
        float* o = out + (size_t)tok * DOUT + colBase;
#pragma unroll
        for (int ni = 0; ni < 4; ++ni) o[ni * 16] = acc[mi][ni][r];
      }
    }
  }
}

__global__ __launch_bounds__(256, 3) void gemm_nolds(
    const unsigned short* __restrict__ a0, const unsigned short* __restrict__ a1,
    const unsigned short* __restrict__ a2, const unsigned short* __restrict__ wb0,
    const unsigned short* __restrict__ wb1, const unsigned short* __restrict__ wb2,
    const int* __restrict__ cnt, const int* __restrict__ bucket,
    float* __restrict__ out) {
  const int z = blockIdx.z;
  if (z == 0)
    gemm_body<1024>(a0, wb0, cnt[0], bucket + 0 * NMAX, out);
  else if (z == 1)
    gemm_body<256>(a1, wb1, cnt[1], bucket + 1 * NMAX, out);
  else
    gemm_body<64>(a2, wb2, cnt[2], bucket + 2 * NMAX, out);
}

extern "C" void kernel_launch(void* const* d_in, const int* in_sizes, int n_in,
                              void* d_out, int out_size, void* d_ws, size_t ws_size,
                              hipStream_t stream) {
  const int* idx = (const int*)d_in[0];
  const float* emb0 = (const float*)d_in[1];
  const float* w0 = (const float*)d_in[2];
  const float* emb1 = (const float*)d_in[3];
  const float* w1 = (const float*)d_in[4];
  const float* emb2 = (const float*)d_in[5];
  const float* w2 = (const float*)d_in[6];
  float* out = (float*)d_out;
  const int N = in_sizes[0];  // 16384

  // ---- workspace layout ----
  char* ws = (char*)d_ws;
  int* cnt = (int*)ws;                              // 64 B
  int* bucket = (int*)(ws + 1024);                  // 3*NMAX ints
  int* blocal = bucket + 3 * NMAX;                  // 3*NMAX ints
  size_t off = 1024 + (size_t)6 * NMAX * 4;
  off = (off + 255) & ~(size_t)255;
  unsigned short* wb0 = (unsigned short*)(ws + off); off += (size_t)DOUT * 1024 * 2;
  unsigned short* wb1 = (unsigned short*)(ws + off); off += (size_t)DOUT * 256 * 2;
  unsigned short* wb2 = (unsigned short*)(ws + off); off += (size_t)DOUT * 64 * 2;
  off = (off + 255) & ~(size_t)255;
  unsigned short* a0 = (unsigned short*)(ws + off); off += (size_t)NMAX * 1024 * 2;
  unsigned short* a1 = (unsigned short*)(ws + off); off += (size_t)NMAX * 256 * 2;
  unsigned short* a2 = (unsigned short*)(ws + off); off += (size_t)NMAX * 64 * 2;

  hipMemsetAsync(cnt, 0, 16 * sizeof(int), stream);

  // classify (64 blocks) + swizzled B build (672 blocks)
  classify_cvt_kernel<<<64 + 672, 256, 0, stream>>>(
      idx, cnt, bucket, blocal, N, w0, w1, w2, wb0, wb1, wb2);

  // gather + swizzle A, all clusters
  dim3 ggrid(1024, 1, 3);
  gather_swz<<<ggrid, 256, 0, stream>>>(emb0, emb1, emb2, blocal, cnt, a0, a1, a2);

  // barrier-free GEMM: x fastest => n-tile pinned per XCD (B L2-resident)
  dim3 grid(DOUT / 128, NMAX / 128, 3);
  gemm_nolds<<<grid, 256, 0, stream>>>(a0, a1, a2, wb0, wb1, wb2, cnt, bucket, out);
}